// Round 15
// baseline (2626.770 us; speedup 1.0000x reference)
//
#include <hip/hip_runtime.h>
#include <math.h>

#define KK 128
#define NTT 128
#define PMAXF 10.0f
#define SP 0.1f          // SIGMA / PMAX
#define LDA2 130         // LDS row stride (float2), even -> 16B-aligned float4 row ops
#define LUT 768          // LU threads: 12 waves = 3/SIMD (R12 was 8 waves = 2/SIMD)

typedef float2 c32;

__device__ __forceinline__ c32 cmul(c32 a, c32 b){
    return make_float2(a.x*b.x - a.y*b.y, a.x*b.y + a.y*b.x);
}
__device__ __forceinline__ c32 cmulc(c32 a, c32 b){ // a * conj(b)
    return make_float2(a.x*b.x + a.y*b.y, a.y*b.x - a.x*b.y);
}
__device__ __forceinline__ c32 cinv(c32 a){
    float d = 1.0f/(a.x*a.x + a.y*a.y);
    return make_float2(a.x*d, -a.y*d);
}

// ---------------- tr_vv of the raw input V (layer 0 only) ----------------
__global__ void k_trvv(const float* __restrict__ V0, float* __restrict__ out){
    float s = 0.f;
    for (int e = blockIdx.x*blockDim.x + threadIdx.x; e < 2*KK*NTT; e += gridDim.x*blockDim.x){
        float v = V0[e]; s += v*v;
    }
    __shared__ float red[4];
    for (int d = 32; d; d >>= 1) s += __shfl_down(s, d);
    int lane = threadIdx.x & 63, w = threadIdx.x >> 6;
    if (!lane) red[w] = s;
    __syncthreads();
    if (!threadIdx.x){
        float t = red[0] + red[1] + red[2] + red[3];
        atomicAdd(out, t);
    }
}

// ---------------- stage 1: P row + per-k scalar chain ----------------
__global__ void k_stage1(const float* __restrict__ Hre, const float* __restrict__ Him,
                         const float* __restrict__ V0re, const float* __restrict__ V0im,
                         const float2* __restrict__ VN, int use_vn,
                         const float* __restrict__ pw2prev,  // null for layer 0
                         const float* __restrict__ trvvp,    // used when layer 0
                         const float* __restrict__ u1, const float* __restrict__ u3,
                         const float* __restrict__ u4, const float* __restrict__ w1,
                         const float* __restrict__ w3,
                         float* __restrict__ wre, float* __restrict__ wim,
                         float* __restrict__ sre, float* __restrict__ sim,
                         float* __restrict__ sumw)
{
    int k = blockIdx.x, j = threadIdx.x;
    __shared__ float hre_s[NTT], him_s[NTT];
    __shared__ float red2[2];
    __shared__ c32 pkk_s;
    hre_s[j] = Hre[k*NTT + j];
    him_s[j] = Him[k*NTT + j];
    __syncthreads();

    float g = 1.0f;
    if (pw2prev) g = sqrtf(PMAXF / *pw2prev);

    float pre = 0.f, pim = 0.f;
    if (use_vn){
        const float2* vr = VN + j*NTT;
        #pragma unroll 4
        for (int n = 0; n < NTT; n++){
            float2 v = vr[n];
            pre += hre_s[n]*v.x - him_s[n]*v.y;
            pim += hre_s[n]*v.y + him_s[n]*v.x;
        }
    } else {
        const float* vr = V0re + j*NTT;
        const float* vi = V0im + j*NTT;
        #pragma unroll 4
        for (int n = 0; n < NTT; n++){
            float a = vr[n], b = vi[n];
            pre += hre_s[n]*a - him_s[n]*b;
            pim += hre_s[n]*b + him_s[n]*a;
        }
    }
    pre *= g; pim *= g;
    if (j == k) pkk_s = make_float2(pre, pim);
    // wave-shuffle reduction of |P|^2 (2 waves, 1 barrier)
    float q = pre*pre + pim*pim;
    #pragma unroll
    for (int d = 32; d; d >>= 1) q += __shfl_down(q, d);
    if ((j & 63) == 0) red2[j >> 6] = q;
    __syncthreads();
    if (j == 0){
        float qq = red2[0] + red2[1];
        float trvv = pw2prev ? PMAXF : *trvvp;
        float A = SP*trvv + qq;
        float invA = 1.0f/A;
        c32 p1 = make_float2(u1[k], u1[KK + k]);
        c32 p3 = make_float2(u3[k], u3[KK + k]);
        c32 p4 = make_float2(u4[k], u4[KK + k]);
        c32 Ainv = make_float2(p1.x*invA + 0.01f*p3.x, p1.y*invA + 0.01f*p3.y);
        c32 Pkk = pkk_s;
        c32 U = cmul(Ainv, Pkk); U.x += p4.x; U.y += p4.y;
        c32 t = cmulc(Pkk, U);                  // Pkk * conj(U)
        c32 E = make_float2(1.0f - t.x, -t.y);
        c32 iE = cinv(E);
        c32 q1 = make_float2(w1[k], w1[KK + k]);
        c32 q3 = make_float2(w3[k], w3[KK + k]);
        c32 W = cmul(q1, iE);
        W.x = 0.1f*W.x + 0.01f*q3.x;
        W.y = 0.1f*W.y + 0.01f*q3.y;
        float u2 = U.x*U.x + U.y*U.y;
        c32 wk = make_float2(u2*W.x, u2*W.y);
        c32 sk = cmul(U, W);
        wre[k] = wk.x; wim[k] = wk.y;
        sre[k] = sk.x; sim[k] = sk.y;
        atomicAdd(&sumw[0], wk.x);
        atomicAdd(&sumw[1], wk.y);
    }
}

// ---------------- build B = 0.1*sum_w*I + H^H diag(w) H ----------------
__global__ void k_bbuild(const float* __restrict__ Hre, const float* __restrict__ Him,
                         const float* __restrict__ wre, const float* __restrict__ wim,
                         const float* __restrict__ sumw, float2* __restrict__ B)
{
    int n = blockIdx.x, m = threadIdx.x;
    __shared__ float cr[KK], ci[KK];
    {
        int k = m;
        c32 h = make_float2(Hre[k*NTT + n], -Him[k*NTT + n]); // conj(H[k,n])
        c32 wk = make_float2(wre[k], wim[k]);
        c32 t = cmul(h, wk);
        cr[k] = t.x; ci[k] = t.y;
    }
    __syncthreads();
    float br = 0.f, bi = 0.f;
    #pragma unroll 4
    for (int k = 0; k < KK; k++){
        float hr = Hre[k*NTT + m], hi = Him[k*NTT + m];
        br += cr[k]*hr - ci[k]*hi;
        bi += cr[k]*hi + ci[k]*hr;
    }
    if (n == m){ br += SP*sumw[0]; bi += SP*sumw[1]; }
    B[n*NTT + m] = make_float2(br, bi);
}

// ---------------- Z matvec body: z_k = vp4[k] * conj(h_k) (512 thr) ----------------
__device__ __forceinline__ void z_body(int k, int t,
                                       const float* __restrict__ p4re,
                                       const float* __restrict__ p4im,
                                       const float* __restrict__ Hre,
                                       const float* __restrict__ Him,
                                       float2* __restrict__ Z)
{
    int r = t >> 2, q = t & 3;
    const float* mre = p4re + (size_t)k*16384 + (size_t)r*128 + q*32;
    const float* mim = p4im + (size_t)k*16384 + (size_t)r*128 + q*32;
    const float* hr4 = Hre + k*NTT + q*32;
    const float* hi4 = Him + k*NTT + q*32;
    float ar = 0.f, ai = 0.f;
    #pragma unroll
    for (int ii = 0; ii < 8; ++ii){
        float4 a = *(const float4*)(mre + 4*ii);
        float4 b = *(const float4*)(mim + 4*ii);
        float4 hr = *(const float4*)(hr4 + 4*ii);
        float4 hi = *(const float4*)(hi4 + 4*ii);
        ar += a.x*hr.x + b.x*hi.x;  ai += b.x*hr.x - a.x*hi.x;
        ar += a.y*hr.y + b.y*hi.y;  ai += b.y*hr.y - a.y*hi.y;
        ar += a.z*hr.z + b.z*hi.z;  ai += b.z*hr.z - a.z*hi.z;
        ar += a.w*hr.w + b.w*hi.w;  ai += b.w*hr.w - a.w*hi.w;
    }
    ar += __shfl_xor(ar, 1); ai += __shfl_xor(ai, 1);
    ar += __shfl_xor(ar, 2); ai += __shfl_xor(ai, 2);
    if (q == 0) Z[k*NTT + r] = make_float2(ar, ai);
}

// ---------------- standalone Z (layer 0 prologue) ----------------
__global__ void __launch_bounds__(512) k_z(const float* __restrict__ p4re,
                                           const float* __restrict__ p4im,
                                           const float* __restrict__ Hre,
                                           const float* __restrict__ Him,
                                           float2* __restrict__ Z)
{
    z_body(blockIdx.x, threadIdx.x, p4re, p4im, Hre, Him, Z);
}

// ---------------- LU v15: R12 structure at 768 threads + dual-row-pair ILP ----------------
// 12 waves = 3/SIMD (vs R12's 2/SIMD) for latency hiding; every phase <= ~100 VGPR
// so no clamp/spill expected (VGPR budget at 3 waves/SIMD is ~170).
// Per panel j (3 barriers):
//  R1: lanes 0-15 diag factor in registers || threads 64+: B2-rest of panel j-1
//      with TWO independent row-pair accumulators per thread (chain ILP x2).
//  R2: t<Rt: B1 || 256<=t<256+Rt: per-row L-TRSM emitting MscT.
//  R3: all 768: B2-priority (cols T0..T0+15).
__global__ void __launch_bounds__(768, 1) k_lu15(const float2* __restrict__ B,
                                                 float2* __restrict__ BT,
                                                 float2* __restrict__ rcg,
                                                 int* __restrict__ permg)
{
    extern __shared__ float2 As[];           // [128][LDA2]
    __shared__ float2 rc_s[KK];
    __shared__ float2 Us[16*17];             // diag-block U rows (padded)
    __shared__ float2 MM[16*16];             // premultiplied B1 coeffs [a2][i]
    __shared__ float2 MscT[16*114];          // MscT[i][rp]
    const int t = threadIdx.x;

    // vectorized load B -> As
    {
        const float4* B4 = (const float4*)B;
        float4* A4 = (float4*)As;            // row stride 65 float4
        for (int e = t; e < KK*64; e += LUT){
            int r = e >> 6, cq = e & 63;
            A4[r*65 + cq] = B4[e];
        }
    }
    __syncthreads();

    for (int j = 0; j < 8; ++j){
        const int J0 = j*16, T0 = J0 + 16, Rt = 128 - T0;

        // =============== Region 1: diag factor || B2-rest(prev) ===============
        if (t < 64){
            if (t < 16){
                const int l = t;
                float2 d[16], rcr[16];
                #pragma unroll
                for (int h = 0; h < 8; ++h){
                    float4 q = *(const float4*)&As[(J0 + l)*LDA2 + J0 + 2*h];
                    d[2*h]   = make_float2(q.x, q.y);
                    d[2*h+1] = make_float2(q.z, q.w);
                }
                #pragma unroll
                for (int ii = 0; ii < 16; ++ii){
                    float2 piv;
                    piv.x = __shfl(d[ii].x, ii);
                    piv.y = __shfl(d[ii].y, ii);
                    float2 rc = cinv(piv);
                    rcr[ii] = rc;
                    if (l == ii) rc_s[J0 + ii] = rc;
                    float2 m = cmul(d[ii], rc);
                    const bool act = (l > ii);
                    #pragma unroll
                    for (int c = ii + 1; c < 16; ++c){
                        float ux = __shfl(d[c].x, ii);
                        float uy = __shfl(d[c].y, ii);
                        if (act){
                            d[c].x -= m.x*ux - m.y*uy;
                            d[c].y -= m.x*uy + m.y*ux;
                        }
                    }
                }
                #pragma unroll
                for (int h = 0; h < 8; ++h)
                    *(float4*)&As[(J0 + l)*LDA2 + J0 + 2*h] =
                        make_float4(d[2*h].x, d[2*h].y, d[2*h+1].x, d[2*h+1].y);
                #pragma unroll
                for (int c = 0; c < 16; ++c) Us[l*17 + c] = d[c];
                if (l >= 1){
                    #pragma unroll
                    for (int i = 0; i < 15; ++i){
                        if (i < l) MM[l*16 + i] = cmul(d[i], rcr[i]);
                    }
                }
            }
        } else if (j > 0){
            // ---- B2-rest of panel j-1: rows >= J0, cols >= T0 ----
            // 704 worker threads: 64 col-pair slots x 11 row groups; each thread
            // carries TWO independent row-pair accumulator sets (ILP x2).
            const int J0p = J0 - 16;
            const int ncp = (128 - T0) >> 1;
            int tt = t - 64;
            int cp = tt & 63, g = tt >> 6;       // 64 col-pair slots, 11 row groups
            if (cp < ncp){
                int c0 = T0 + 2*cp;
                float4 u2[16];
                #pragma unroll
                for (int i = 0; i < 16; ++i)
                    u2[i] = *(const float4*)&As[(J0p + i)*LDA2 + c0];
                int nb = (128 - J0) >> 1;
                for (int rb = g; rb < nb; rb += 22){
                    int rb2 = rb + 11;
                    bool has2 = (rb2 < nb);
                    int rbs = has2 ? rb2 : rb;
                    int r0_ = J0 + 2*rb;
                    int r2_ = J0 + 2*rbs;
                    float4 a0_ = *(const float4*)&As[r0_*LDA2 + c0];
                    float4 a1_ = *(const float4*)&As[(r0_ + 1)*LDA2 + c0];
                    float4 b0_ = *(const float4*)&As[r2_*LDA2 + c0];
                    float4 b1_ = *(const float4*)&As[(r2_ + 1)*LDA2 + c0];
                    #pragma unroll
                    for (int i = 0; i < 16; ++i){
                        float4 mm = *(const float4*)&MscT[i*114 + 2*rb];
                        float4 mn = *(const float4*)&MscT[i*114 + 2*rbs];
                        float4 u = u2[i];
                        a0_.x -= mm.x*u.x - mm.y*u.y;  a0_.y -= mm.x*u.y + mm.y*u.x;
                        a0_.z -= mm.x*u.z - mm.y*u.w;  a0_.w -= mm.x*u.w + mm.y*u.z;
                        a1_.x -= mm.z*u.x - mm.w*u.y;  a1_.y -= mm.z*u.y + mm.w*u.x;
                        a1_.z -= mm.z*u.z - mm.w*u.w;  a1_.w -= mm.z*u.w + mm.w*u.z;
                        b0_.x -= mn.x*u.x - mn.y*u.y;  b0_.y -= mn.x*u.y + mn.y*u.x;
                        b0_.z -= mn.x*u.z - mn.y*u.w;  b0_.w -= mn.x*u.w + mn.y*u.z;
                        b1_.x -= mn.z*u.x - mn.w*u.y;  b1_.y -= mn.z*u.y + mn.w*u.x;
                        b1_.z -= mn.z*u.z - mn.w*u.w;  b1_.w -= mn.z*u.w + mn.w*u.z;
                    }
                    *(float4*)&As[r0_*LDA2 + c0] = a0_;
                    *(float4*)&As[(r0_ + 1)*LDA2 + c0] = a1_;
                    if (has2){
                        *(float4*)&As[r2_*LDA2 + c0] = b0_;
                        *(float4*)&As[(r2_ + 1)*LDA2 + c0] = b1_;
                    }
                }
            }
        }
        __syncthreads();

        if (j == 7) break;

        // =============== Region 2: B1 || L-TRSM (+MscT) ===============
        if (t < Rt){
            int c = T0 + t;
            float2 u[16];
            #pragma unroll
            for (int i = 0; i < 16; ++i) u[i] = As[(J0 + i)*LDA2 + c];
            #pragma unroll
            for (int a2 = 1; a2 < 16; ++a2){
                #pragma unroll
                for (int i = 0; i < 16; ++i){
                    if (i < a2){
                        float2 mm = MM[a2*16 + i];    // broadcast
                        u[a2].x -= mm.x*u[i].x - mm.y*u[i].y;
                        u[a2].y -= mm.x*u[i].y + mm.y*u[i].x;
                    }
                }
            }
            #pragma unroll
            for (int a2 = 1; a2 < 16; ++a2) As[(J0 + a2)*LDA2 + c] = u[a2];
        } else if (t >= 256 && t < 256 + Rt){
            int r = T0 + (t - 256);
            float2 v[16], tv[16];
            #pragma unroll
            for (int h = 0; h < 8; ++h){
                float4 q = *(const float4*)&As[r*LDA2 + J0 + 2*h];
                v[2*h]   = make_float2(q.x, q.y);
                v[2*h+1] = make_float2(q.z, q.w);
            }
            #pragma unroll
            for (int c = 0; c < 16; ++c){
                #pragma unroll
                for (int i = 0; i < 16; ++i){
                    if (i < c){
                        float2 uu = Us[i*17 + c];     // broadcast
                        float2 ti = tv[i];
                        v[c].x -= ti.x*uu.x - ti.y*uu.y;
                        v[c].y -= ti.x*uu.y + ti.y*uu.x;
                    }
                }
                tv[c] = cmul(v[c], rc_s[J0 + c]);     // broadcast rc
            }
            #pragma unroll
            for (int h = 0; h < 8; ++h)
                *(float4*)&As[r*LDA2 + J0 + 2*h] =
                    make_float4(v[2*h].x, v[2*h].y, v[2*h+1].x, v[2*h+1].y);
            int rp = r - T0;
            #pragma unroll
            for (int i = 0; i < 16; ++i) MscT[i*114 + rp] = tv[i];
        }
        __syncthreads();

        // =============== Region 3: B2-priority (cols T0..T0+15) ===============
        {
            int cp = t & 7, g = t >> 3;       // 8 col-pairs, 96 row-slots
            int c0 = T0 + 2*cp;
            float4 u2[16];
            #pragma unroll
            for (int i = 0; i < 16; ++i)
                u2[i] = *(const float4*)&As[(J0 + i)*LDA2 + c0];
            int nb = Rt >> 1;
            for (int rb = g; rb < nb; rb += 96){
                int r0_ = T0 + 2*rb;
                float4 a0_ = *(const float4*)&As[r0_*LDA2 + c0];
                float4 a1_ = *(const float4*)&As[(r0_ + 1)*LDA2 + c0];
                #pragma unroll
                for (int i = 0; i < 16; ++i){
                    float4 mm = *(const float4*)&MscT[i*114 + 2*rb];
                    float4 u = u2[i];
                    a0_.x -= mm.x*u.x - mm.y*u.y;  a0_.y -= mm.x*u.y + mm.y*u.x;
                    a0_.z -= mm.x*u.z - mm.y*u.w;  a0_.w -= mm.x*u.w + mm.y*u.z;
                    a1_.x -= mm.z*u.x - mm.w*u.y;  a1_.y -= mm.z*u.y + mm.w*u.x;
                    a1_.z -= mm.z*u.z - mm.w*u.w;  a1_.w -= mm.z*u.w + mm.w*u.z;
                }
                *(float4*)&As[r0_*LDA2 + c0] = a0_;
                *(float4*)&As[(r0_ + 1)*LDA2 + c0] = a1_;
            }
        }
        __syncthreads();
    }

    // write BT (column-major) + rc + perm
    for (int e = t; e < KK*NTT; e += LUT){
        int c = e >> 7, r = e & 127;
        BT[e] = As[r*LDA2 + c];
    }
    if (t < KK){ rcg[t] = rc_s[t]; permg[t] = t; }
}

// ---------------- solve body (device): wave 0 solves B x = conj(H[c,:])^T -> xv ----------------
__device__ __forceinline__ void solve_col(const float2* __restrict__ BT,
                                          const float2* __restrict__ rc_s,
                                          const int* __restrict__ permg,
                                          const float* __restrict__ Hre,
                                          const float* __restrict__ Him,
                                          int c, int lane, float2* __restrict__ xv)
{
    int r0 = lane, r1 = lane + 64;
    int o0 = permg[r0], o1 = permg[r1];
    float2 b0 = make_float2(Hre[c*NTT + o0], -Him[c*NTT + o0]);
    float2 b1 = make_float2(Hre[c*NTT + o1], -Him[c*NTT + o1]);

    float2 cur0[8], cur1[8];
    // -------- forward: L (unit diag, lazy scaled) --------
    #pragma unroll
    for (int jj = 0; jj < 8; jj++){ cur0[jj] = BT[jj*NTT + r0]; cur1[jj] = BT[jj*NTT + r1]; }
    for (int ib = 0; ib < 16; ib++){
        float2 n0[8], n1[8];
        if (ib < 15){
            int nb = (ib + 1)*8;
            #pragma unroll
            for (int jj = 0; jj < 8; jj++){ n0[jj] = BT[(nb + jj)*NTT + r0]; n1[jj] = BT[(nb + jj)*NTT + r1]; }
        }
        #pragma unroll
        for (int jj = 0; jj < 8; jj++){
            int i = ib*8 + jj;
            float xr, xi;
            if (i < 64){ xr = __shfl(b0.x, i);      xi = __shfl(b0.y, i); }
            else       { xr = __shfl(b1.x, i - 64); xi = __shfl(b1.y, i - 64); }
            float2 rc = rc_s[i];
            float tr = rc.x*xr - rc.y*xi, ti = rc.x*xi + rc.y*xr;
            float2 l0 = cur0[jj], l1 = cur1[jj];
            if (r0 > i){ b0.x -= l0.x*tr - l0.y*ti; b0.y -= l0.x*ti + l0.y*tr; }
            if (r1 > i){ b1.x -= l1.x*tr - l1.y*ti; b1.y -= l1.x*ti + l1.y*tr; }
        }
        if (ib < 15){
            #pragma unroll
            for (int jj = 0; jj < 8; jj++){ cur0[jj] = n0[jj]; cur1[jj] = n1[jj]; }
        }
    }
    // -------- backward: U --------
    #pragma unroll
    for (int jj = 0; jj < 8; jj++){ cur0[jj] = BT[(120 + jj)*NTT + r0]; cur1[jj] = BT[(120 + jj)*NTT + r1]; }
    for (int ib = 15; ib >= 0; ib--){
        float2 n0[8], n1[8];
        if (ib > 0){
            int nb = (ib - 1)*8;
            #pragma unroll
            for (int jj = 0; jj < 8; jj++){ n0[jj] = BT[(nb + jj)*NTT + r0]; n1[jj] = BT[(nb + jj)*NTT + r1]; }
        }
        #pragma unroll
        for (int jj = 7; jj >= 0; jj--){
            int i = ib*8 + jj;
            float yr, yi;
            if (i < 64){ yr = __shfl(b0.x, i);      yi = __shfl(b0.y, i); }
            else       { yr = __shfl(b1.x, i - 64); yi = __shfl(b1.y, i - 64); }
            float2 rc = rc_s[i];
            float xr = rc.x*yr - rc.y*yi, xi = rc.x*yi + rc.y*yr;
            if (r0 == i){ b0.x = xr; b0.y = xi; }
            if (r1 == i){ b1.x = xr; b1.y = xi; }
            float2 u0 = cur0[jj], u1v = cur1[jj];
            if (r0 < i){ b0.x -= u0.x*xr - u0.y*xi; b0.y -= u0.x*xi + u0.y*xr; }
            if (r1 < i){ b1.x -= u1v.x*xr - u1v.y*xi; b1.y -= u1v.x*xi + u1v.y*xr; }
        }
        if (ib > 0){
            #pragma unroll
            for (int jj = 0; jj < 8; jj++){ cur0[jj] = n0[jj]; cur1[jj] = n1[jj]; }
        }
    }
    xv[r0] = b0;
    xv[r1] = b1;
}

// ---------------- fused solve + Y matvec + combine + next-layer Z (mid layers) ----------------
// Blocks 0..127: solve column k, Y matvec, combine using Zcur.
// Blocks 128..255: compute Z for layer l+1 into Znext (skipped when p4n == null).
__global__ void __launch_bounds__(512) k_solvemv(const float2* __restrict__ BT,
                                                 const float2* __restrict__ rcg,
                                                 const int* __restrict__ permg,
                                                 const float* __restrict__ Hre, const float* __restrict__ Him,
                                                 const float* __restrict__ p2re, const float* __restrict__ p2im,
                                                 const float2* __restrict__ Zcur,
                                                 const float* __restrict__ sre, const float* __restrict__ sim,
                                                 const float* __restrict__ p1re, const float* __restrict__ p1im,
                                                 float2* __restrict__ VN, float* __restrict__ pw2,
                                                 const float* __restrict__ p4nre, const float* __restrict__ p4nim,
                                                 float2* __restrict__ Znext)
{
    if (blockIdx.x >= 128){
        if (p4nre) z_body(blockIdx.x - 128, threadIdx.x, p4nre, p4nim, Hre, Him, Znext);
        return;
    }
    int k = blockIdx.x;
    int t = threadIdx.x;
    __shared__ float2 xv[NTT];
    __shared__ float2 rc_s[KK];
    __shared__ float red[8];

    // issue p2 loads early (independent of the solve)
    int r = t >> 2, q = t & 3;
    const float* mre = p2re + (size_t)k*16384 + (size_t)r*128 + q*32;
    const float* mim = p2im + (size_t)k*16384 + (size_t)r*128 + q*32;
    float4 pa[8], pb[8];
    #pragma unroll
    for (int ii = 0; ii < 8; ++ii){
        pa[ii] = *(const float4*)(mre + 4*ii);
        pb[ii] = *(const float4*)(mim + 4*ii);
    }
    if (t < 64){
        rc_s[t] = rcg[t];
        rc_s[t + 64] = rcg[t + 64];
        solve_col(BT, rc_s, permg, Hre, Him, k, t, xv);
    }
    __syncthreads();

    float ar = 0.f, ai = 0.f;
    #pragma unroll
    for (int ii = 0; ii < 8; ++ii){
        float4 a = pa[ii], b = pb[ii];
        float2 x0 = xv[q*32 + 4*ii], x1 = xv[q*32 + 4*ii + 1];
        float2 x2 = xv[q*32 + 4*ii + 2], x3 = xv[q*32 + 4*ii + 3];
        ar += a.x*x0.x - b.x*x0.y;  ai += a.x*x0.y + b.x*x0.x;
        ar += a.y*x1.x - b.y*x1.y;  ai += a.y*x1.y + b.y*x1.x;
        ar += a.z*x2.x - b.z*x2.y;  ai += a.z*x2.y + b.z*x2.x;
        ar += a.w*x3.x - b.w*x3.y;  ai += a.w*x3.y + b.w*x3.x;
    }
    ar += __shfl_xor(ar, 1); ai += __shfl_xor(ai, 1);
    ar += __shfl_xor(ar, 2); ai += __shfl_xor(ai, 2);
    float pwl = 0.f;
    if (q == 0){
        float2 z = Zcur[k*NTT + r];
        c32 s = make_float2(sre[k], sim[k]);
        float2 y = make_float2(ar + 0.01f*z.x, ai + 0.01f*z.y);
        c32 v = cmul(s, y);
        v.x += p1re[k*NTT + r]; v.y += p1im[k*NTT + r];
        VN[k*NTT + r] = v;
        pwl = v.x*v.x + v.y*v.y;
    }
    for (int d = 32; d; d >>= 1) pwl += __shfl_down(pwl, d);
    int lane = t & 63, w = t >> 6;
    if (!lane) red[w] = pwl;
    __syncthreads();
    if (!t){
        float tt = 0.f;
        #pragma unroll
        for (int w2 = 0; w2 < 8; ++w2) tt += red[w2];
        atomicAdd(pw2, tt);
    }
}

// ---------------- fused solve + final output (final layer) ----------------
__global__ void __launch_bounds__(64) k_solvefin(const float2* __restrict__ BT,
                                                 const float2* __restrict__ rcg,
                                                 const int* __restrict__ permg,
                                                 const float* __restrict__ Hre, const float* __restrict__ Him,
                                                 const float* __restrict__ sre, const float* __restrict__ sim,
                                                 float2* __restrict__ VN, float* __restrict__ pw2)
{
    int c = blockIdx.x;
    int lane = threadIdx.x;
    __shared__ float2 xv[NTT];
    __shared__ float2 rc_s[KK];
    rc_s[lane] = rcg[lane];
    rc_s[lane + 64] = rcg[lane + 64];
    solve_col(BT, rc_s, permg, Hre, Him, c, lane, xv);

    c32 s = make_float2(sre[c], sim[c]);
    float2 v0 = cmul(s, xv[lane]);
    float2 v1 = cmul(s, xv[lane + 64]);
    VN[c*NTT + lane] = v0;
    VN[c*NTT + lane + 64] = v1;
    float pwl = v0.x*v0.x + v0.y*v0.y + v1.x*v1.x + v1.y*v1.y;
    for (int d = 32; d; d >>= 1) pwl += __shfl_down(pwl, d);
    if (!lane) atomicAdd(pw2, pwl);
}

// ---------------- output write (normalized, split planes) ----------------
__global__ void k_write(const float2* __restrict__ VN, const float* __restrict__ pw2,
                        float* __restrict__ out)
{
    float gsc = sqrtf(PMAXF / *pw2);
    for (int e = blockIdx.x*blockDim.x + threadIdx.x; e < KK*NTT; e += gridDim.x*blockDim.x){
        float2 v = VN[e];
        out[e] = gsc*v.x;
        out[KK*NTT + e] = gsc*v.y;
    }
}

extern "C" void kernel_launch(void* const* d_in, const int* in_sizes, int n_in,
                              void* d_out, int out_size, void* d_ws, size_t ws_size,
                              hipStream_t stream)
{
    const float* V0  = (const float*)d_in[0];
    const float* H   = (const float*)d_in[1];
    const float* mu1 = (const float*)d_in[2];
    const float* mu3 = (const float*)d_in[3];
    const float* mu4 = (const float*)d_in[4];
    const float* mw1 = (const float*)d_in[5];
    const float* mw3 = (const float*)d_in[6];
    const float* mv1 = (const float*)d_in[7];
    const float* mv2 = (const float*)d_in[8];
    const float* mv4 = (const float*)d_in[9];
    const float* fu1 = (const float*)d_in[10];
    const float* fu3 = (const float*)d_in[11];
    const float* fu4 = (const float*)d_in[12];
    const float* fw1 = (const float*)d_in[13];
    const float* fw3 = (const float*)d_in[14];

    float* ws = (float*)d_ws;
    float*  acc  = ws;                       // [9][4]: sumw_re, sumw_im, pw2, pad ; trvv at ws[40]
    float*  wre  = ws + 64;
    float*  wim  = ws + 192;
    float*  sre  = ws + 320;
    float*  sim  = ws + 448;
    float2* B    = (float2*)(ws + 1024);     // 16384 complex
    float2* rc   = (float2*)(ws + 33792);    // 128
    int*    perm = (int*)  (ws + 34048);     // 128
    float2* Zb1  = (float2*)(ws + 34176);    // 16384 complex
    float2* Zb0  = (float2*)(ws + 99712);    // 16384 complex
    float2* VN   = (float2*)(ws + 132480);   // 16384
    float2* BT   = (float2*)(ws + 165248);   // 16384

    const int LU_LDS = KK*LDA2*sizeof(float2);   // 133,120 B dynamic
    (void)hipFuncSetAttribute((const void*)k_lu15,
                              hipFuncAttributeMaxDynamicSharedMemorySize, LU_LDS);

    hipMemsetAsync(ws, 0, 64*sizeof(float), stream);
    k_trvv<<<64, 256, 0, stream>>>(V0, ws + 40);

    const float* Hre = H;
    const float* Him = H + 16384;

    // Z for layer 0
    k_z<<<128, 512, 0, stream>>>(mv4, mv4 + 2097152, Hre, Him, Zb0);

    for (int l = 0; l < 9; l++){
        bool fin = (l == 8);
        const float* u1 = fin ? fu1 : mu1 + (size_t)l*256;
        const float* u3 = fin ? fu3 : mu3 + (size_t)l*256;
        const float* u4 = fin ? fu4 : mu4 + (size_t)l*256;
        const float* w1 = fin ? fw1 : mw1 + (size_t)l*256;
        const float* w3 = fin ? fw3 : mw3 + (size_t)l*256;

        k_stage1<<<128, 128, 0, stream>>>(Hre, Him, V0, V0 + 16384, VN, (l > 0) ? 1 : 0,
                                          (l > 0) ? (acc + (l - 1)*4 + 2) : nullptr,
                                          ws + 40,
                                          u1, u3, u4, w1, w3,
                                          wre, wim, sre, sim, acc + l*4);
        k_bbuild<<<128, 128, 0, stream>>>(Hre, Him, wre, wim, acc + l*4, B);
        k_lu15<<<1, LUT, LU_LDS, stream>>>(B, BT, rc, perm);

        if (!fin){
            const float* p2 = mv2 + (size_t)l*4194304;
            const float* p1 = mv1 + (size_t)l*32768;
            float2* Zcur  = (l & 1) ? Zb1 : Zb0;
            float2* Znext = (l & 1) ? Zb0 : Zb1;
            const float* p4n = (l + 1 < 8) ? (mv4 + (size_t)(l + 1)*4194304) : nullptr;
            k_solvemv<<<256, 512, 0, stream>>>(BT, rc, perm, Hre, Him,
                                               p2, p2 + 2097152, Zcur,
                                               sre, sim, p1, p1 + 16384,
                                               VN, acc + l*4 + 2,
                                               p4n, p4n ? (p4n + 2097152) : nullptr, Znext);
        } else {
            k_solvefin<<<128, 64, 0, stream>>>(BT, rc, perm, Hre, Him,
                                               sre, sim, VN, acc + l*4 + 2);
            k_write<<<64, 256, 0, stream>>>(VN, acc + l*4 + 2, (float*)d_out);
        }
    }
}

// Round 16
// 1676.811 us; speedup vs baseline: 1.5665x; 1.5665x over previous
//
#include <hip/hip_runtime.h>
#include <math.h>

#define KK 128
#define NTT 128
#define PMAXF 10.0f
#define SP 0.1f          // SIGMA / PMAX
#define LDA2 130         // LDS row stride (float2), even -> 16B-aligned float4 row ops
#define LUT 768          // LU threads: 12 waves = 3/SIMD, launch_bounds(768,3) pins VGPR cap at 170

typedef float2 c32;

__device__ __forceinline__ c32 cmul(c32 a, c32 b){
    return make_float2(a.x*b.x - a.y*b.y, a.x*b.y + a.y*b.x);
}
__device__ __forceinline__ c32 cmulc(c32 a, c32 b){ // a * conj(b)
    return make_float2(a.x*b.x + a.y*b.y, a.y*b.x - a.x*b.y);
}
__device__ __forceinline__ c32 cinv(c32 a){
    float d = 1.0f/(a.x*a.x + a.y*a.y);
    return make_float2(a.x*d, -a.y*d);
}

// ---------------- tr_vv of the raw input V (layer 0 only) ----------------
__global__ void k_trvv(const float* __restrict__ V0, float* __restrict__ out){
    float s = 0.f;
    for (int e = blockIdx.x*blockDim.x + threadIdx.x; e < 2*KK*NTT; e += gridDim.x*blockDim.x){
        float v = V0[e]; s += v*v;
    }
    __shared__ float red[4];
    for (int d = 32; d; d >>= 1) s += __shfl_down(s, d);
    int lane = threadIdx.x & 63, w = threadIdx.x >> 6;
    if (!lane) red[w] = s;
    __syncthreads();
    if (!threadIdx.x){
        float t = red[0] + red[1] + red[2] + red[3];
        atomicAdd(out, t);
    }
}

// ---------------- stage 1: P row + per-k scalar chain ----------------
__global__ void k_stage1(const float* __restrict__ Hre, const float* __restrict__ Him,
                         const float* __restrict__ V0re, const float* __restrict__ V0im,
                         const float2* __restrict__ VN, int use_vn,
                         const float* __restrict__ pw2prev,  // null for layer 0
                         const float* __restrict__ trvvp,    // used when layer 0
                         const float* __restrict__ u1, const float* __restrict__ u3,
                         const float* __restrict__ u4, const float* __restrict__ w1,
                         const float* __restrict__ w3,
                         float* __restrict__ wre, float* __restrict__ wim,
                         float* __restrict__ sre, float* __restrict__ sim,
                         float* __restrict__ sumw)
{
    int k = blockIdx.x, j = threadIdx.x;
    __shared__ float hre_s[NTT], him_s[NTT];
    __shared__ float red2[2];
    __shared__ c32 pkk_s;
    hre_s[j] = Hre[k*NTT + j];
    him_s[j] = Him[k*NTT + j];
    __syncthreads();

    float g = 1.0f;
    if (pw2prev) g = sqrtf(PMAXF / *pw2prev);

    float pre = 0.f, pim = 0.f;
    if (use_vn){
        const float2* vr = VN + j*NTT;
        #pragma unroll 4
        for (int n = 0; n < NTT; n++){
            float2 v = vr[n];
            pre += hre_s[n]*v.x - him_s[n]*v.y;
            pim += hre_s[n]*v.y + him_s[n]*v.x;
        }
    } else {
        const float* vr = V0re + j*NTT;
        const float* vi = V0im + j*NTT;
        #pragma unroll 4
        for (int n = 0; n < NTT; n++){
            float a = vr[n], b = vi[n];
            pre += hre_s[n]*a - him_s[n]*b;
            pim += hre_s[n]*b + him_s[n]*a;
        }
    }
    pre *= g; pim *= g;
    if (j == k) pkk_s = make_float2(pre, pim);
    // wave-shuffle reduction of |P|^2 (2 waves, 1 barrier)
    float q = pre*pre + pim*pim;
    #pragma unroll
    for (int d = 32; d; d >>= 1) q += __shfl_down(q, d);
    if ((j & 63) == 0) red2[j >> 6] = q;
    __syncthreads();
    if (j == 0){
        float qq = red2[0] + red2[1];
        float trvv = pw2prev ? PMAXF : *trvvp;
        float A = SP*trvv + qq;
        float invA = 1.0f/A;
        c32 p1 = make_float2(u1[k], u1[KK + k]);
        c32 p3 = make_float2(u3[k], u3[KK + k]);
        c32 p4 = make_float2(u4[k], u4[KK + k]);
        c32 Ainv = make_float2(p1.x*invA + 0.01f*p3.x, p1.y*invA + 0.01f*p3.y);
        c32 Pkk = pkk_s;
        c32 U = cmul(Ainv, Pkk); U.x += p4.x; U.y += p4.y;
        c32 t = cmulc(Pkk, U);                  // Pkk * conj(U)
        c32 E = make_float2(1.0f - t.x, -t.y);
        c32 iE = cinv(E);
        c32 q1 = make_float2(w1[k], w1[KK + k]);
        c32 q3 = make_float2(w3[k], w3[KK + k]);
        c32 W = cmul(q1, iE);
        W.x = 0.1f*W.x + 0.01f*q3.x;
        W.y = 0.1f*W.y + 0.01f*q3.y;
        float u2 = U.x*U.x + U.y*U.y;
        c32 wk = make_float2(u2*W.x, u2*W.y);
        c32 sk = cmul(U, W);
        wre[k] = wk.x; wim[k] = wk.y;
        sre[k] = sk.x; sim[k] = sk.y;
        atomicAdd(&sumw[0], wk.x);
        atomicAdd(&sumw[1], wk.y);
    }
}

// ---------------- build B = 0.1*sum_w*I + H^H diag(w) H ----------------
__global__ void k_bbuild(const float* __restrict__ Hre, const float* __restrict__ Him,
                         const float* __restrict__ wre, const float* __restrict__ wim,
                         const float* __restrict__ sumw, float2* __restrict__ B)
{
    int n = blockIdx.x, m = threadIdx.x;
    __shared__ float cr[KK], ci[KK];
    {
        int k = m;
        c32 h = make_float2(Hre[k*NTT + n], -Him[k*NTT + n]); // conj(H[k,n])
        c32 wk = make_float2(wre[k], wim[k]);
        c32 t = cmul(h, wk);
        cr[k] = t.x; ci[k] = t.y;
    }
    __syncthreads();
    float br = 0.f, bi = 0.f;
    #pragma unroll 4
    for (int k = 0; k < KK; k++){
        float hr = Hre[k*NTT + m], hi = Him[k*NTT + m];
        br += cr[k]*hr - ci[k]*hi;
        bi += cr[k]*hi + ci[k]*hr;
    }
    if (n == m){ br += SP*sumw[0]; bi += SP*sumw[1]; }
    B[n*NTT + m] = make_float2(br, bi);
}

// ---------------- Z matvec body: z_k = vp4[k] * conj(h_k) (512 thr) ----------------
__device__ __forceinline__ void z_body(int k, int t,
                                       const float* __restrict__ p4re,
                                       const float* __restrict__ p4im,
                                       const float* __restrict__ Hre,
                                       const float* __restrict__ Him,
                                       float2* __restrict__ Z)
{
    int r = t >> 2, q = t & 3;
    const float* mre = p4re + (size_t)k*16384 + (size_t)r*128 + q*32;
    const float* mim = p4im + (size_t)k*16384 + (size_t)r*128 + q*32;
    const float* hr4 = Hre + k*NTT + q*32;
    const float* hi4 = Him + k*NTT + q*32;
    float ar = 0.f, ai = 0.f;
    #pragma unroll
    for (int ii = 0; ii < 8; ++ii){
        float4 a = *(const float4*)(mre + 4*ii);
        float4 b = *(const float4*)(mim + 4*ii);
        float4 hr = *(const float4*)(hr4 + 4*ii);
        float4 hi = *(const float4*)(hi4 + 4*ii);
        ar += a.x*hr.x + b.x*hi.x;  ai += b.x*hr.x - a.x*hi.x;
        ar += a.y*hr.y + b.y*hi.y;  ai += b.y*hr.y - a.y*hi.y;
        ar += a.z*hr.z + b.z*hi.z;  ai += b.z*hr.z - a.z*hi.z;
        ar += a.w*hr.w + b.w*hi.w;  ai += b.w*hr.w - a.w*hi.w;
    }
    ar += __shfl_xor(ar, 1); ai += __shfl_xor(ai, 1);
    ar += __shfl_xor(ar, 2); ai += __shfl_xor(ai, 2);
    if (q == 0) Z[k*NTT + r] = make_float2(ar, ai);
}

// ---------------- standalone Z (layer 0 prologue) ----------------
__global__ void __launch_bounds__(512) k_z(const float* __restrict__ p4re,
                                           const float* __restrict__ p4im,
                                           const float* __restrict__ Hre,
                                           const float* __restrict__ Him,
                                           float2* __restrict__ Z)
{
    z_body(blockIdx.x, threadIdx.x, p4re, p4im, Hre, Him, Z);
}

// ---------------- LU v16: R14 structure at 768 threads, launch_bounds(768,3) ----------------
// (768,3) pins the VGPR cap at 512/3 = 170 (R15's (768,1) let the compiler clamp
// to 84 and spill). Pure index remaps of R14; no per-thread state growth.
// Per panel j (3 barriers):
//  R1: lanes 0-15 diag factor in registers || threads 64+: B2-rest of panel j-1
//      (704 workers: 64 col-pairs x 11 row groups).
//  R2: t<Rt: B1 || 256<=t<256+Rt: per-row L-TRSM emitting MscT.
//  R3: all 768: B2-priority (cols T0..T0+15), 96 row-slots.
__global__ void __launch_bounds__(768, 3) k_lu16(const float2* __restrict__ B,
                                                 float2* __restrict__ BT,
                                                 float2* __restrict__ rcg,
                                                 int* __restrict__ permg)
{
    extern __shared__ float2 As[];           // [128][LDA2]
    __shared__ float2 rc_s[KK];
    __shared__ float2 Us[16*17];             // diag-block U rows (padded)
    __shared__ float2 MM[16*16];             // premultiplied B1 coeffs [a2][i]
    __shared__ float2 MscT[16*114];          // MscT[i][rp]
    const int t = threadIdx.x;

    // vectorized load B -> As
    {
        const float4* B4 = (const float4*)B;
        float4* A4 = (float4*)As;            // row stride 65 float4
        for (int e = t; e < KK*64; e += LUT){
            int r = e >> 6, cq = e & 63;
            A4[r*65 + cq] = B4[e];
        }
    }
    __syncthreads();

    for (int j = 0; j < 8; ++j){
        const int J0 = j*16, T0 = J0 + 16, Rt = 128 - T0;

        // =============== Region 1: diag factor || B2-rest(prev) ===============
        if (t < 64){
            if (t < 16){
                const int l = t;
                float2 d[16], rcr[16];
                #pragma unroll
                for (int h = 0; h < 8; ++h){
                    float4 q = *(const float4*)&As[(J0 + l)*LDA2 + J0 + 2*h];
                    d[2*h]   = make_float2(q.x, q.y);
                    d[2*h+1] = make_float2(q.z, q.w);
                }
                #pragma unroll
                for (int ii = 0; ii < 16; ++ii){
                    float2 piv;
                    piv.x = __shfl(d[ii].x, ii);
                    piv.y = __shfl(d[ii].y, ii);
                    float2 rc = cinv(piv);
                    rcr[ii] = rc;
                    if (l == ii) rc_s[J0 + ii] = rc;
                    float2 m = cmul(d[ii], rc);
                    const bool act = (l > ii);
                    #pragma unroll
                    for (int c = ii + 1; c < 16; ++c){
                        float ux = __shfl(d[c].x, ii);
                        float uy = __shfl(d[c].y, ii);
                        if (act){
                            d[c].x -= m.x*ux - m.y*uy;
                            d[c].y -= m.x*uy + m.y*ux;
                        }
                    }
                }
                #pragma unroll
                for (int h = 0; h < 8; ++h)
                    *(float4*)&As[(J0 + l)*LDA2 + J0 + 2*h] =
                        make_float4(d[2*h].x, d[2*h].y, d[2*h+1].x, d[2*h+1].y);
                #pragma unroll
                for (int c = 0; c < 16; ++c) Us[l*17 + c] = d[c];
                if (l >= 1){
                    #pragma unroll
                    for (int i = 0; i < 15; ++i){
                        if (i < l) MM[l*16 + i] = cmul(d[i], rcr[i]);
                    }
                }
            }
        } else if (j > 0){
            // ---- B2-rest of panel j-1: rows >= J0, cols >= T0 (11 row groups) ----
            const int J0p = J0 - 16;
            const int ncp = (128 - T0) >> 1;
            int tt = t - 64;
            int cp = tt & 63, g = tt >> 6;       // 64 col-pair slots, 11 row groups
            if (cp < ncp){
                int c0 = T0 + 2*cp;
                float4 u2[16];
                #pragma unroll
                for (int i = 0; i < 16; ++i)
                    u2[i] = *(const float4*)&As[(J0p + i)*LDA2 + c0];
                int nb = (128 - J0) >> 1;
                for (int rb = g; rb < nb; rb += 11){
                    int r0_ = J0 + 2*rb;
                    float4 a0_ = *(const float4*)&As[r0_*LDA2 + c0];
                    float4 a1_ = *(const float4*)&As[(r0_ + 1)*LDA2 + c0];
                    #pragma unroll
                    for (int i = 0; i < 16; ++i){
                        float4 mm = *(const float4*)&MscT[i*114 + 2*rb];
                        float4 u = u2[i];
                        a0_.x -= mm.x*u.x - mm.y*u.y;  a0_.y -= mm.x*u.y + mm.y*u.x;
                        a0_.z -= mm.x*u.z - mm.y*u.w;  a0_.w -= mm.x*u.w + mm.y*u.z;
                        a1_.x -= mm.z*u.x - mm.w*u.y;  a1_.y -= mm.z*u.y + mm.w*u.x;
                        a1_.z -= mm.z*u.z - mm.w*u.w;  a1_.w -= mm.z*u.w + mm.w*u.z;
                    }
                    *(float4*)&As[r0_*LDA2 + c0] = a0_;
                    *(float4*)&As[(r0_ + 1)*LDA2 + c0] = a1_;
                }
            }
        }
        __syncthreads();

        if (j == 7) break;

        // =============== Region 2: B1 || L-TRSM (+MscT) ===============
        if (t < Rt){
            int c = T0 + t;
            float2 u[16];
            #pragma unroll
            for (int i = 0; i < 16; ++i) u[i] = As[(J0 + i)*LDA2 + c];
            #pragma unroll
            for (int a2 = 1; a2 < 16; ++a2){
                #pragma unroll
                for (int i = 0; i < 16; ++i){
                    if (i < a2){
                        float2 mm = MM[a2*16 + i];    // broadcast
                        u[a2].x -= mm.x*u[i].x - mm.y*u[i].y;
                        u[a2].y -= mm.x*u[i].y + mm.y*u[i].x;
                    }
                }
            }
            #pragma unroll
            for (int a2 = 1; a2 < 16; ++a2) As[(J0 + a2)*LDA2 + c] = u[a2];
        } else if (t >= 256 && t < 256 + Rt){
            int r = T0 + (t - 256);
            float2 v[16], tv[16];
            #pragma unroll
            for (int h = 0; h < 8; ++h){
                float4 q = *(const float4*)&As[r*LDA2 + J0 + 2*h];
                v[2*h]   = make_float2(q.x, q.y);
                v[2*h+1] = make_float2(q.z, q.w);
            }
            #pragma unroll
            for (int c = 0; c < 16; ++c){
                #pragma unroll
                for (int i = 0; i < 16; ++i){
                    if (i < c){
                        float2 uu = Us[i*17 + c];     // broadcast
                        float2 ti = tv[i];
                        v[c].x -= ti.x*uu.x - ti.y*uu.y;
                        v[c].y -= ti.x*uu.y + ti.y*uu.x;
                    }
                }
                tv[c] = cmul(v[c], rc_s[J0 + c]);     // broadcast rc
            }
            #pragma unroll
            for (int h = 0; h < 8; ++h)
                *(float4*)&As[r*LDA2 + J0 + 2*h] =
                    make_float4(v[2*h].x, v[2*h].y, v[2*h+1].x, v[2*h+1].y);
            int rp = r - T0;
            #pragma unroll
            for (int i = 0; i < 16; ++i) MscT[i*114 + rp] = tv[i];
        }
        __syncthreads();

        // =============== Region 3: B2-priority (cols T0..T0+15) ===============
        {
            int cp = t & 7, g = t >> 3;       // 8 col-pairs, 96 row-slots
            int c0 = T0 + 2*cp;
            float4 u2[16];
            #pragma unroll
            for (int i = 0; i < 16; ++i)
                u2[i] = *(const float4*)&As[(J0 + i)*LDA2 + c0];
            int nb = Rt >> 1;
            for (int rb = g; rb < nb; rb += 96){
                int r0_ = T0 + 2*rb;
                float4 a0_ = *(const float4*)&As[r0_*LDA2 + c0];
                float4 a1_ = *(const float4*)&As[(r0_ + 1)*LDA2 + c0];
                #pragma unroll
                for (int i = 0; i < 16; ++i){
                    float4 mm = *(const float4*)&MscT[i*114 + 2*rb];
                    float4 u = u2[i];
                    a0_.x -= mm.x*u.x - mm.y*u.y;  a0_.y -= mm.x*u.y + mm.y*u.x;
                    a0_.z -= mm.x*u.z - mm.y*u.w;  a0_.w -= mm.x*u.w + mm.y*u.z;
                    a1_.x -= mm.z*u.x - mm.w*u.y;  a1_.y -= mm.z*u.y + mm.w*u.x;
                    a1_.z -= mm.z*u.z - mm.w*u.w;  a1_.w -= mm.z*u.w + mm.w*u.z;
                }
                *(float4*)&As[r0_*LDA2 + c0] = a0_;
                *(float4*)&As[(r0_ + 1)*LDA2 + c0] = a1_;
            }
        }
        __syncthreads();
    }

    // write BT (column-major) + rc + perm
    for (int e = t; e < KK*NTT; e += LUT){
        int c = e >> 7, r = e & 127;
        BT[e] = As[r*LDA2 + c];
    }
    if (t < KK){ rcg[t] = rc_s[t]; permg[t] = t; }
}

// ---------------- solve body (device): wave 0 solves B x = conj(H[c,:])^T -> xv ----------------
__device__ __forceinline__ void solve_col(const float2* __restrict__ BT,
                                          const float2* __restrict__ rc_s,
                                          const int* __restrict__ permg,
                                          const float* __restrict__ Hre,
                                          const float* __restrict__ Him,
                                          int c, int lane, float2* __restrict__ xv)
{
    int r0 = lane, r1 = lane + 64;
    int o0 = permg[r0], o1 = permg[r1];
    float2 b0 = make_float2(Hre[c*NTT + o0], -Him[c*NTT + o0]);
    float2 b1 = make_float2(Hre[c*NTT + o1], -Him[c*NTT + o1]);

    float2 cur0[8], cur1[8];
    // -------- forward: L (unit diag, lazy scaled) --------
    #pragma unroll
    for (int jj = 0; jj < 8; jj++){ cur0[jj] = BT[jj*NTT + r0]; cur1[jj] = BT[jj*NTT + r1]; }
    for (int ib = 0; ib < 16; ib++){
        float2 n0[8], n1[8];
        if (ib < 15){
            int nb = (ib + 1)*8;
            #pragma unroll
            for (int jj = 0; jj < 8; jj++){ n0[jj] = BT[(nb + jj)*NTT + r0]; n1[jj] = BT[(nb + jj)*NTT + r1]; }
        }
        #pragma unroll
        for (int jj = 0; jj < 8; jj++){
            int i = ib*8 + jj;
            float xr, xi;
            if (i < 64){ xr = __shfl(b0.x, i);      xi = __shfl(b0.y, i); }
            else       { xr = __shfl(b1.x, i - 64); xi = __shfl(b1.y, i - 64); }
            float2 rc = rc_s[i];
            float tr = rc.x*xr - rc.y*xi, ti = rc.x*xi + rc.y*xr;
            float2 l0 = cur0[jj], l1 = cur1[jj];
            if (r0 > i){ b0.x -= l0.x*tr - l0.y*ti; b0.y -= l0.x*ti + l0.y*tr; }
            if (r1 > i){ b1.x -= l1.x*tr - l1.y*ti; b1.y -= l1.x*ti + l1.y*tr; }
        }
        if (ib < 15){
            #pragma unroll
            for (int jj = 0; jj < 8; jj++){ cur0[jj] = n0[jj]; cur1[jj] = n1[jj]; }
        }
    }
    // -------- backward: U --------
    #pragma unroll
    for (int jj = 0; jj < 8; jj++){ cur0[jj] = BT[(120 + jj)*NTT + r0]; cur1[jj] = BT[(120 + jj)*NTT + r1]; }
    for (int ib = 15; ib >= 0; ib--){
        float2 n0[8], n1[8];
        if (ib > 0){
            int nb = (ib - 1)*8;
            #pragma unroll
            for (int jj = 0; jj < 8; jj++){ n0[jj] = BT[(nb + jj)*NTT + r0]; n1[jj] = BT[(nb + jj)*NTT + r1]; }
        }
        #pragma unroll
        for (int jj = 7; jj >= 0; jj--){
            int i = ib*8 + jj;
            float yr, yi;
            if (i < 64){ yr = __shfl(b0.x, i);      yi = __shfl(b0.y, i); }
            else       { yr = __shfl(b1.x, i - 64); yi = __shfl(b1.y, i - 64); }
            float2 rc = rc_s[i];
            float xr = rc.x*yr - rc.y*yi, xi = rc.x*yi + rc.y*yr;
            if (r0 == i){ b0.x = xr; b0.y = xi; }
            if (r1 == i){ b1.x = xr; b1.y = xi; }
            float2 u0 = cur0[jj], u1v = cur1[jj];
            if (r0 < i){ b0.x -= u0.x*xr - u0.y*xi; b0.y -= u0.x*xi + u0.y*xr; }
            if (r1 < i){ b1.x -= u1v.x*xr - u1v.y*xi; b1.y -= u1v.x*xi + u1v.y*xr; }
        }
        if (ib > 0){
            #pragma unroll
            for (int jj = 0; jj < 8; jj++){ cur0[jj] = n0[jj]; cur1[jj] = n1[jj]; }
        }
    }
    xv[r0] = b0;
    xv[r1] = b1;
}

// ---------------- fused solve + Y matvec + combine + next-layer Z (mid layers) ----------------
// Blocks 0..127: solve column k, Y matvec, combine using Zcur.
// Blocks 128..255: compute Z for layer l+1 into Znext (skipped when p4n == null).
__global__ void __launch_bounds__(512) k_solvemv(const float2* __restrict__ BT,
                                                 const float2* __restrict__ rcg,
                                                 const int* __restrict__ permg,
                                                 const float* __restrict__ Hre, const float* __restrict__ Him,
                                                 const float* __restrict__ p2re, const float* __restrict__ p2im,
                                                 const float2* __restrict__ Zcur,
                                                 const float* __restrict__ sre, const float* __restrict__ sim,
                                                 const float* __restrict__ p1re, const float* __restrict__ p1im,
                                                 float2* __restrict__ VN, float* __restrict__ pw2,
                                                 const float* __restrict__ p4nre, const float* __restrict__ p4nim,
                                                 float2* __restrict__ Znext)
{
    if (blockIdx.x >= 128){
        if (p4nre) z_body(blockIdx.x - 128, threadIdx.x, p4nre, p4nim, Hre, Him, Znext);
        return;
    }
    int k = blockIdx.x;
    int t = threadIdx.x;
    __shared__ float2 xv[NTT];
    __shared__ float2 rc_s[KK];
    __shared__ float red[8];

    // issue p2 loads early (independent of the solve)
    int r = t >> 2, q = t & 3;
    const float* mre = p2re + (size_t)k*16384 + (size_t)r*128 + q*32;
    const float* mim = p2im + (size_t)k*16384 + (size_t)r*128 + q*32;
    float4 pa[8], pb[8];
    #pragma unroll
    for (int ii = 0; ii < 8; ++ii){
        pa[ii] = *(const float4*)(mre + 4*ii);
        pb[ii] = *(const float4*)(mim + 4*ii);
    }
    if (t < 64){
        rc_s[t] = rcg[t];
        rc_s[t + 64] = rcg[t + 64];
        solve_col(BT, rc_s, permg, Hre, Him, k, t, xv);
    }
    __syncthreads();

    float ar = 0.f, ai = 0.f;
    #pragma unroll
    for (int ii = 0; ii < 8; ++ii){
        float4 a = pa[ii], b = pb[ii];
        float2 x0 = xv[q*32 + 4*ii], x1 = xv[q*32 + 4*ii + 1];
        float2 x2 = xv[q*32 + 4*ii + 2], x3 = xv[q*32 + 4*ii + 3];
        ar += a.x*x0.x - b.x*x0.y;  ai += a.x*x0.y + b.x*x0.x;
        ar += a.y*x1.x - b.y*x1.y;  ai += a.y*x1.y + b.y*x1.x;
        ar += a.z*x2.x - b.z*x2.y;  ai += a.z*x2.y + b.z*x2.x;
        ar += a.w*x3.x - b.w*x3.y;  ai += a.w*x3.y + b.w*x3.x;
    }
    ar += __shfl_xor(ar, 1); ai += __shfl_xor(ai, 1);
    ar += __shfl_xor(ar, 2); ai += __shfl_xor(ai, 2);
    float pwl = 0.f;
    if (q == 0){
        float2 z = Zcur[k*NTT + r];
        c32 s = make_float2(sre[k], sim[k]);
        float2 y = make_float2(ar + 0.01f*z.x, ai + 0.01f*z.y);
        c32 v = cmul(s, y);
        v.x += p1re[k*NTT + r]; v.y += p1im[k*NTT + r];
        VN[k*NTT + r] = v;
        pwl = v.x*v.x + v.y*v.y;
    }
    for (int d = 32; d; d >>= 1) pwl += __shfl_down(pwl, d);
    int lane = t & 63, w = t >> 6;
    if (!lane) red[w] = pwl;
    __syncthreads();
    if (!t){
        float tt = 0.f;
        #pragma unroll
        for (int w2 = 0; w2 < 8; ++w2) tt += red[w2];
        atomicAdd(pw2, tt);
    }
}

// ---------------- fused solve + final output (final layer) ----------------
__global__ void __launch_bounds__(64) k_solvefin(const float2* __restrict__ BT,
                                                 const float2* __restrict__ rcg,
                                                 const int* __restrict__ permg,
                                                 const float* __restrict__ Hre, const float* __restrict__ Him,
                                                 const float* __restrict__ sre, const float* __restrict__ sim,
                                                 float2* __restrict__ VN, float* __restrict__ pw2)
{
    int c = blockIdx.x;
    int lane = threadIdx.x;
    __shared__ float2 xv[NTT];
    __shared__ float2 rc_s[KK];
    rc_s[lane] = rcg[lane];
    rc_s[lane + 64] = rcg[lane + 64];
    solve_col(BT, rc_s, permg, Hre, Him, c, lane, xv);

    c32 s = make_float2(sre[c], sim[c]);
    float2 v0 = cmul(s, xv[lane]);
    float2 v1 = cmul(s, xv[lane + 64]);
    VN[c*NTT + lane] = v0;
    VN[c*NTT + lane + 64] = v1;
    float pwl = v0.x*v0.x + v0.y*v0.y + v1.x*v1.x + v1.y*v1.y;
    for (int d = 32; d; d >>= 1) pwl += __shfl_down(pwl, d);
    if (!lane) atomicAdd(pw2, pwl);
}

// ---------------- output write (normalized, split planes) ----------------
__global__ void k_write(const float2* __restrict__ VN, const float* __restrict__ pw2,
                        float* __restrict__ out)
{
    float gsc = sqrtf(PMAXF / *pw2);
    for (int e = blockIdx.x*blockDim.x + threadIdx.x; e < KK*NTT; e += gridDim.x*blockDim.x){
        float2 v = VN[e];
        out[e] = gsc*v.x;
        out[KK*NTT + e] = gsc*v.y;
    }
}

extern "C" void kernel_launch(void* const* d_in, const int* in_sizes, int n_in,
                              void* d_out, int out_size, void* d_ws, size_t ws_size,
                              hipStream_t stream)
{
    const float* V0  = (const float*)d_in[0];
    const float* H   = (const float*)d_in[1];
    const float* mu1 = (const float*)d_in[2];
    const float* mu3 = (const float*)d_in[3];
    const float* mu4 = (const float*)d_in[4];
    const float* mw1 = (const float*)d_in[5];
    const float* mw3 = (const float*)d_in[6];
    const float* mv1 = (const float*)d_in[7];
    const float* mv2 = (const float*)d_in[8];
    const float* mv4 = (const float*)d_in[9];
    const float* fu1 = (const float*)d_in[10];
    const float* fu3 = (const float*)d_in[11];
    const float* fu4 = (const float*)d_in[12];
    const float* fw1 = (const float*)d_in[13];
    const float* fw3 = (const float*)d_in[14];

    float* ws = (float*)d_ws;
    float*  acc  = ws;                       // [9][4]: sumw_re, sumw_im, pw2, pad ; trvv at ws[40]
    float*  wre  = ws + 64;
    float*  wim  = ws + 192;
    float*  sre  = ws + 320;
    float*  sim  = ws + 448;
    float2* B    = (float2*)(ws + 1024);     // 16384 complex
    float2* rc   = (float2*)(ws + 33792);    // 128
    int*    perm = (int*)  (ws + 34048);     // 128
    float2* Zb1  = (float2*)(ws + 34176);    // 16384 complex
    float2* Zb0  = (float2*)(ws + 99712);    // 16384 complex
    float2* VN   = (float2*)(ws + 132480);   // 16384
    float2* BT   = (float2*)(ws + 165248);   // 16384

    const int LU_LDS = KK*LDA2*sizeof(float2);   // 133,120 B dynamic
    (void)hipFuncSetAttribute((const void*)k_lu16,
                              hipFuncAttributeMaxDynamicSharedMemorySize, LU_LDS);

    hipMemsetAsync(ws, 0, 64*sizeof(float), stream);
    k_trvv<<<64, 256, 0, stream>>>(V0, ws + 40);

    const float* Hre = H;
    const float* Him = H + 16384;

    // Z for layer 0
    k_z<<<128, 512, 0, stream>>>(mv4, mv4 + 2097152, Hre, Him, Zb0);

    for (int l = 0; l < 9; l++){
        bool fin = (l == 8);
        const float* u1 = fin ? fu1 : mu1 + (size_t)l*256;
        const float* u3 = fin ? fu3 : mu3 + (size_t)l*256;
        const float* u4 = fin ? fu4 : mu4 + (size_t)l*256;
        const float* w1 = fin ? fw1 : mw1 + (size_t)l*256;
        const float* w3 = fin ? fw3 : mw3 + (size_t)l*256;

        k_stage1<<<128, 128, 0, stream>>>(Hre, Him, V0, V0 + 16384, VN, (l > 0) ? 1 : 0,
                                          (l > 0) ? (acc + (l - 1)*4 + 2) : nullptr,
                                          ws + 40,
                                          u1, u3, u4, w1, w3,
                                          wre, wim, sre, sim, acc + l*4);
        k_bbuild<<<128, 128, 0, stream>>>(Hre, Him, wre, wim, acc + l*4, B);
        k_lu16<<<1, LUT, LU_LDS, stream>>>(B, BT, rc, perm);

        if (!fin){
            const float* p2 = mv2 + (size_t)l*4194304;
            const float* p1 = mv1 + (size_t)l*32768;
            float2* Zcur  = (l & 1) ? Zb1 : Zb0;
            float2* Znext = (l & 1) ? Zb0 : Zb1;
            const float* p4n = (l + 1 < 8) ? (mv4 + (size_t)(l + 1)*4194304) : nullptr;
            k_solvemv<<<256, 512, 0, stream>>>(BT, rc, perm, Hre, Him,
                                               p2, p2 + 2097152, Zcur,
                                               sre, sim, p1, p1 + 16384,
                                               VN, acc + l*4 + 2,
                                               p4n, p4n ? (p4n + 2097152) : nullptr, Znext);
        } else {
            k_solvefin<<<128, 64, 0, stream>>>(BT, rc, perm, Hre, Him,
                                               sre, sim, VN, acc + l*4 + 2);
            k_write<<<64, 256, 0, stream>>>(VN, acc + l*4 + 2, (float*)d_out);
        }
    }
}

// Round 17
// 1545.881 us; speedup vs baseline: 1.6992x; 1.0847x over previous
//
#include <hip/hip_runtime.h>
#include <math.h>

#define KK 128
#define NTT 128
#define PMAXF 10.0f
#define SP 0.1f          // SIGMA / PMAX
#define LDA2 130         // LDS row stride (float2), even -> 16B-aligned float4 row ops

typedef float2 c32;

__device__ __forceinline__ c32 cmul(c32 a, c32 b){
    return make_float2(a.x*b.x - a.y*b.y, a.x*b.y + a.y*b.x);
}
__device__ __forceinline__ c32 cmulc(c32 a, c32 b){ // a * conj(b)
    return make_float2(a.x*b.x + a.y*b.y, a.y*b.x - a.x*b.y);
}
__device__ __forceinline__ c32 cinv(c32 a){
    float d = 1.0f/(a.x*a.x + a.y*a.y);
    return make_float2(a.x*d, -a.y*d);
}

// ---------------- tr_vv of the raw input V (layer 0 only) ----------------
__global__ void k_trvv(const float* __restrict__ V0, float* __restrict__ out){
    float s = 0.f;
    for (int e = blockIdx.x*blockDim.x + threadIdx.x; e < 2*KK*NTT; e += gridDim.x*blockDim.x){
        float v = V0[e]; s += v*v;
    }
    __shared__ float red[4];
    for (int d = 32; d; d >>= 1) s += __shfl_down(s, d);
    int lane = threadIdx.x & 63, w = threadIdx.x >> 6;
    if (!lane) red[w] = s;
    __syncthreads();
    if (!threadIdx.x){
        float t = red[0] + red[1] + red[2] + red[3];
        atomicAdd(out, t);
    }
}

// ---------------- stage 1: P row + per-k scalar chain ----------------
__global__ void k_stage1(const float* __restrict__ Hre, const float* __restrict__ Him,
                         const float* __restrict__ V0re, const float* __restrict__ V0im,
                         const float2* __restrict__ VN, int use_vn,
                         const float* __restrict__ pw2prev,  // null for layer 0
                         const float* __restrict__ trvvp,    // used when layer 0
                         const float* __restrict__ u1, const float* __restrict__ u3,
                         const float* __restrict__ u4, const float* __restrict__ w1,
                         const float* __restrict__ w3,
                         float* __restrict__ wre, float* __restrict__ wim,
                         float* __restrict__ sre, float* __restrict__ sim,
                         float* __restrict__ sumw)
{
    int k = blockIdx.x, j = threadIdx.x;
    __shared__ float hre_s[NTT], him_s[NTT];
    __shared__ float red2[2];
    __shared__ c32 pkk_s;
    hre_s[j] = Hre[k*NTT + j];
    him_s[j] = Him[k*NTT + j];
    __syncthreads();

    float g = 1.0f;
    if (pw2prev) g = sqrtf(PMAXF / *pw2prev);

    float pre = 0.f, pim = 0.f;
    if (use_vn){
        const float2* vr = VN + j*NTT;
        #pragma unroll 4
        for (int n = 0; n < NTT; n++){
            float2 v = vr[n];
            pre += hre_s[n]*v.x - him_s[n]*v.y;
            pim += hre_s[n]*v.y + him_s[n]*v.x;
        }
    } else {
        const float* vr = V0re + j*NTT;
        const float* vi = V0im + j*NTT;
        #pragma unroll 4
        for (int n = 0; n < NTT; n++){
            float a = vr[n], b = vi[n];
            pre += hre_s[n]*a - him_s[n]*b;
            pim += hre_s[n]*b + him_s[n]*a;
        }
    }
    pre *= g; pim *= g;
    if (j == k) pkk_s = make_float2(pre, pim);
    // wave-shuffle reduction of |P|^2 (2 waves, 1 barrier)
    float q = pre*pre + pim*pim;
    #pragma unroll
    for (int d = 32; d; d >>= 1) q += __shfl_down(q, d);
    if ((j & 63) == 0) red2[j >> 6] = q;
    __syncthreads();
    if (j == 0){
        float qq = red2[0] + red2[1];
        float trvv = pw2prev ? PMAXF : *trvvp;
        float A = SP*trvv + qq;
        float invA = 1.0f/A;
        c32 p1 = make_float2(u1[k], u1[KK + k]);
        c32 p3 = make_float2(u3[k], u3[KK + k]);
        c32 p4 = make_float2(u4[k], u4[KK + k]);
        c32 Ainv = make_float2(p1.x*invA + 0.01f*p3.x, p1.y*invA + 0.01f*p3.y);
        c32 Pkk = pkk_s;
        c32 U = cmul(Ainv, Pkk); U.x += p4.x; U.y += p4.y;
        c32 t = cmulc(Pkk, U);                  // Pkk * conj(U)
        c32 E = make_float2(1.0f - t.x, -t.y);
        c32 iE = cinv(E);
        c32 q1 = make_float2(w1[k], w1[KK + k]);
        c32 q3 = make_float2(w3[k], w3[KK + k]);
        c32 W = cmul(q1, iE);
        W.x = 0.1f*W.x + 0.01f*q3.x;
        W.y = 0.1f*W.y + 0.01f*q3.y;
        float u2 = U.x*U.x + U.y*U.y;
        c32 wk = make_float2(u2*W.x, u2*W.y);
        c32 sk = cmul(U, W);
        wre[k] = wk.x; wim[k] = wk.y;
        sre[k] = sk.x; sim[k] = sk.y;
        atomicAdd(&sumw[0], wk.x);
        atomicAdd(&sumw[1], wk.y);
    }
}

// ---------------- build B = 0.1*sum_w*I + H^H diag(w) H ----------------
__global__ void k_bbuild(const float* __restrict__ Hre, const float* __restrict__ Him,
                         const float* __restrict__ wre, const float* __restrict__ wim,
                         const float* __restrict__ sumw, float2* __restrict__ B)
{
    int n = blockIdx.x, m = threadIdx.x;
    __shared__ float cr[KK], ci[KK];
    {
        int k = m;
        c32 h = make_float2(Hre[k*NTT + n], -Him[k*NTT + n]); // conj(H[k,n])
        c32 wk = make_float2(wre[k], wim[k]);
        c32 t = cmul(h, wk);
        cr[k] = t.x; ci[k] = t.y;
    }
    __syncthreads();
    float br = 0.f, bi = 0.f;
    #pragma unroll 4
    for (int k = 0; k < KK; k++){
        float hr = Hre[k*NTT + m], hi = Him[k*NTT + m];
        br += cr[k]*hr - ci[k]*hi;
        bi += cr[k]*hi + ci[k]*hr;
    }
    if (n == m){ br += SP*sumw[0]; bi += SP*sumw[1]; }
    B[n*NTT + m] = make_float2(br, bi);
}

// ---------------- Z matvec body: z_k = vp4[k] * conj(h_k) (512 thr) ----------------
__device__ __forceinline__ void z_body(int k, int t,
                                       const float* __restrict__ p4re,
                                       const float* __restrict__ p4im,
                                       const float* __restrict__ Hre,
                                       const float* __restrict__ Him,
                                       float2* __restrict__ Z)
{
    int r = t >> 2, q = t & 3;
    const float* mre = p4re + (size_t)k*16384 + (size_t)r*128 + q*32;
    const float* mim = p4im + (size_t)k*16384 + (size_t)r*128 + q*32;
    const float* hr4 = Hre + k*NTT + q*32;
    const float* hi4 = Him + k*NTT + q*32;
    float ar = 0.f, ai = 0.f;
    #pragma unroll
    for (int ii = 0; ii < 8; ++ii){
        float4 a = *(const float4*)(mre + 4*ii);
        float4 b = *(const float4*)(mim + 4*ii);
        float4 hr = *(const float4*)(hr4 + 4*ii);
        float4 hi = *(const float4*)(hi4 + 4*ii);
        ar += a.x*hr.x + b.x*hi.x;  ai += b.x*hr.x - a.x*hi.x;
        ar += a.y*hr.y + b.y*hi.y;  ai += b.y*hr.y - a.y*hi.y;
        ar += a.z*hr.z + b.z*hi.z;  ai += b.z*hr.z - a.z*hi.z;
        ar += a.w*hr.w + b.w*hi.w;  ai += b.w*hr.w - a.w*hi.w;
    }
    ar += __shfl_xor(ar, 1); ai += __shfl_xor(ai, 1);
    ar += __shfl_xor(ar, 2); ai += __shfl_xor(ai, 2);
    if (q == 0) Z[k*NTT + r] = make_float2(ar, ai);
}

// ---------------- standalone Z (layer 0 prologue) ----------------
__global__ void __launch_bounds__(512) k_z(const float* __restrict__ p4re,
                                           const float* __restrict__ p4im,
                                           const float* __restrict__ Hre,
                                           const float* __restrict__ Him,
                                           float2* __restrict__ Z)
{
    z_body(blockIdx.x, threadIdx.x, p4re, p4im, Hre, Him, Z);
}

// ---------------- LU v17: R14 structure @512thr + dual-row-pair ILP in B2-rest ----------------
// (512,1) proven to allocate 128 VGPRs. B2-rest: each thread carries TWO independent
// row-pair accumulator tiles (ILP x2 on the dominant dependency chain).
// VGPR budget: u2[16]=64 + 4 acc float4=16 + temps ~20 => ~100 < 128 (no spill).
// Per panel j (3 barriers):
//  R1: lanes 0-15 diag factor in registers || threads 64+: B2-rest of panel j-1.
//  R2: t<Rt: B1 || 256<=t<256+Rt: per-row L-TRSM emitting MscT.
//  R3: all 512: B2-priority (cols T0..T0+15).
__global__ void __launch_bounds__(512, 1) k_lu17(const float2* __restrict__ B,
                                                 float2* __restrict__ BT,
                                                 float2* __restrict__ rcg,
                                                 int* __restrict__ permg)
{
    extern __shared__ float2 As[];           // [128][LDA2]
    __shared__ float2 rc_s[KK];
    __shared__ float2 Us[16*17];             // diag-block U rows (padded)
    __shared__ float2 MM[16*16];             // premultiplied B1 coeffs [a2][i]
    __shared__ float2 MscT[16*114];          // MscT[i][rp]
    const int t = threadIdx.x;

    // vectorized load B -> As
    {
        const float4* B4 = (const float4*)B;
        float4* A4 = (float4*)As;            // row stride 65 float4
        for (int e = t; e < KK*64; e += 512){
            int r = e >> 6, cq = e & 63;
            A4[r*65 + cq] = B4[e];
        }
    }
    __syncthreads();

    for (int j = 0; j < 8; ++j){
        const int J0 = j*16, T0 = J0 + 16, Rt = 128 - T0;

        // =============== Region 1: diag factor || B2-rest(prev) ===============
        if (t < 64){
            if (t < 16){
                const int l = t;
                float2 d[16], rcr[16];
                #pragma unroll
                for (int h = 0; h < 8; ++h){
                    float4 q = *(const float4*)&As[(J0 + l)*LDA2 + J0 + 2*h];
                    d[2*h]   = make_float2(q.x, q.y);
                    d[2*h+1] = make_float2(q.z, q.w);
                }
                #pragma unroll
                for (int ii = 0; ii < 16; ++ii){
                    float2 piv;
                    piv.x = __shfl(d[ii].x, ii);
                    piv.y = __shfl(d[ii].y, ii);
                    float2 rc = cinv(piv);
                    rcr[ii] = rc;
                    if (l == ii) rc_s[J0 + ii] = rc;
                    float2 m = cmul(d[ii], rc);
                    const bool act = (l > ii);
                    #pragma unroll
                    for (int c = ii + 1; c < 16; ++c){
                        float ux = __shfl(d[c].x, ii);
                        float uy = __shfl(d[c].y, ii);
                        if (act){
                            d[c].x -= m.x*ux - m.y*uy;
                            d[c].y -= m.x*uy + m.y*ux;
                        }
                    }
                }
                #pragma unroll
                for (int h = 0; h < 8; ++h)
                    *(float4*)&As[(J0 + l)*LDA2 + J0 + 2*h] =
                        make_float4(d[2*h].x, d[2*h].y, d[2*h+1].x, d[2*h+1].y);
                #pragma unroll
                for (int c = 0; c < 16; ++c) Us[l*17 + c] = d[c];
                if (l >= 1){
                    #pragma unroll
                    for (int i = 0; i < 15; ++i){
                        if (i < l) MM[l*16 + i] = cmul(d[i], rcr[i]);
                    }
                }
            }
        } else if (j > 0){
            // ---- B2-rest of panel j-1: rows >= J0, cols >= T0 ----
            // 448 workers: 64 col-pairs x 7 row groups; each thread carries TWO
            // independent row-pair tiles per iteration (stride 14) for chain ILP.
            const int J0p = J0 - 16;
            const int ncp = (128 - T0) >> 1;
            int tt = t - 64;
            int cp = tt & 63, g = tt >> 6;       // 64 col-pair slots, 7 row groups
            if (cp < ncp){
                int c0 = T0 + 2*cp;
                float4 u2[16];
                #pragma unroll
                for (int i = 0; i < 16; ++i)
                    u2[i] = *(const float4*)&As[(J0p + i)*LDA2 + c0];
                int nb = (128 - J0) >> 1;
                for (int rb = g; rb < nb; rb += 14){
                    int rb2 = rb + 7;
                    bool has2 = (rb2 < nb);
                    int rbs = has2 ? rb2 : rb;
                    int r0_ = J0 + 2*rb;
                    int r2_ = J0 + 2*rbs;
                    float4 a0_ = *(const float4*)&As[r0_*LDA2 + c0];
                    float4 a1_ = *(const float4*)&As[(r0_ + 1)*LDA2 + c0];
                    float4 b0_ = *(const float4*)&As[r2_*LDA2 + c0];
                    float4 b1_ = *(const float4*)&As[(r2_ + 1)*LDA2 + c0];
                    #pragma unroll
                    for (int i = 0; i < 16; ++i){
                        float4 mm = *(const float4*)&MscT[i*114 + 2*rb];
                        float4 mn = *(const float4*)&MscT[i*114 + 2*rbs];
                        float4 u = u2[i];
                        a0_.x -= mm.x*u.x - mm.y*u.y;  a0_.y -= mm.x*u.y + mm.y*u.x;
                        a0_.z -= mm.x*u.z - mm.y*u.w;  a0_.w -= mm.x*u.w + mm.y*u.z;
                        a1_.x -= mm.z*u.x - mm.w*u.y;  a1_.y -= mm.z*u.y + mm.w*u.x;
                        a1_.z -= mm.z*u.z - mm.w*u.w;  a1_.w -= mm.z*u.w + mm.w*u.z;
                        b0_.x -= mn.x*u.x - mn.y*u.y;  b0_.y -= mn.x*u.y + mn.y*u.x;
                        b0_.z -= mn.x*u.z - mn.y*u.w;  b0_.w -= mn.x*u.w + mn.y*u.z;
                        b1_.x -= mn.z*u.x - mn.w*u.y;  b1_.y -= mn.z*u.y + mn.w*u.x;
                        b1_.z -= mn.z*u.z - mn.w*u.w;  b1_.w -= mn.z*u.w + mn.w*u.z;
                    }
                    *(float4*)&As[r0_*LDA2 + c0] = a0_;
                    *(float4*)&As[(r0_ + 1)*LDA2 + c0] = a1_;
                    if (has2){
                        *(float4*)&As[r2_*LDA2 + c0] = b0_;
                        *(float4*)&As[(r2_ + 1)*LDA2 + c0] = b1_;
                    }
                }
            }
        }
        __syncthreads();

        if (j == 7) break;

        // =============== Region 2: B1 || L-TRSM (+MscT) ===============
        if (t < Rt){
            int c = T0 + t;
            float2 u[16];
            #pragma unroll
            for (int i = 0; i < 16; ++i) u[i] = As[(J0 + i)*LDA2 + c];
            #pragma unroll
            for (int a2 = 1; a2 < 16; ++a2){
                #pragma unroll
                for (int i = 0; i < 16; ++i){
                    if (i < a2){
                        float2 mm = MM[a2*16 + i];    // broadcast
                        u[a2].x -= mm.x*u[i].x - mm.y*u[i].y;
                        u[a2].y -= mm.x*u[i].y + mm.y*u[i].x;
                    }
                }
            }
            #pragma unroll
            for (int a2 = 1; a2 < 16; ++a2) As[(J0 + a2)*LDA2 + c] = u[a2];
        } else if (t >= 256 && t < 256 + Rt){
            int r = T0 + (t - 256);
            float2 v[16], tv[16];
            #pragma unroll
            for (int h = 0; h < 8; ++h){
                float4 q = *(const float4*)&As[r*LDA2 + J0 + 2*h];
                v[2*h]   = make_float2(q.x, q.y);
                v[2*h+1] = make_float2(q.z, q.w);
            }
            #pragma unroll
            for (int c = 0; c < 16; ++c){
                #pragma unroll
                for (int i = 0; i < 16; ++i){
                    if (i < c){
                        float2 uu = Us[i*17 + c];     // broadcast
                        float2 ti = tv[i];
                        v[c].x -= ti.x*uu.x - ti.y*uu.y;
                        v[c].y -= ti.x*uu.y + ti.y*uu.x;
                    }
                }
                tv[c] = cmul(v[c], rc_s[J0 + c]);     // broadcast rc
            }
            #pragma unroll
            for (int h = 0; h < 8; ++h)
                *(float4*)&As[r*LDA2 + J0 + 2*h] =
                    make_float4(v[2*h].x, v[2*h].y, v[2*h+1].x, v[2*h+1].y);
            int rp = r - T0;
            #pragma unroll
            for (int i = 0; i < 16; ++i) MscT[i*114 + rp] = tv[i];
        }
        __syncthreads();

        // =============== Region 3: B2-priority (cols T0..T0+15) ===============
        {
            int cp = t & 7, g = t >> 3;       // 8 col-pairs, 64 row-slots
            int c0 = T0 + 2*cp;
            float4 u2[16];
            #pragma unroll
            for (int i = 0; i < 16; ++i)
                u2[i] = *(const float4*)&As[(J0 + i)*LDA2 + c0];
            int nb = Rt >> 1;
            for (int rb = g; rb < nb; rb += 64){
                int r0_ = T0 + 2*rb;
                float4 a0_ = *(const float4*)&As[r0_*LDA2 + c0];
                float4 a1_ = *(const float4*)&As[(r0_ + 1)*LDA2 + c0];
                #pragma unroll
                for (int i = 0; i < 16; ++i){
                    float4 mm = *(const float4*)&MscT[i*114 + 2*rb];
                    float4 u = u2[i];
                    a0_.x -= mm.x*u.x - mm.y*u.y;  a0_.y -= mm.x*u.y + mm.y*u.x;
                    a0_.z -= mm.x*u.z - mm.y*u.w;  a0_.w -= mm.x*u.w + mm.y*u.z;
                    a1_.x -= mm.z*u.x - mm.w*u.y;  a1_.y -= mm.z*u.y + mm.w*u.x;
                    a1_.z -= mm.z*u.z - mm.w*u.w;  a1_.w -= mm.z*u.w + mm.w*u.z;
                }
                *(float4*)&As[r0_*LDA2 + c0] = a0_;
                *(float4*)&As[(r0_ + 1)*LDA2 + c0] = a1_;
            }
        }
        __syncthreads();
    }

    // write BT (column-major) + rc + perm
    for (int e = t; e < KK*NTT; e += 512){
        int c = e >> 7, r = e & 127;
        BT[e] = As[r*LDA2 + c];
    }
    if (t < KK){ rcg[t] = rc_s[t]; permg[t] = t; }
}

// ---------------- solve body (device): wave 0 solves B x = conj(H[c,:])^T -> xv ----------------
__device__ __forceinline__ void solve_col(const float2* __restrict__ BT,
                                          const float2* __restrict__ rc_s,
                                          const int* __restrict__ permg,
                                          const float* __restrict__ Hre,
                                          const float* __restrict__ Him,
                                          int c, int lane, float2* __restrict__ xv)
{
    int r0 = lane, r1 = lane + 64;
    int o0 = permg[r0], o1 = permg[r1];
    float2 b0 = make_float2(Hre[c*NTT + o0], -Him[c*NTT + o0]);
    float2 b1 = make_float2(Hre[c*NTT + o1], -Him[c*NTT + o1]);

    float2 cur0[8], cur1[8];
    // -------- forward: L (unit diag, lazy scaled) --------
    #pragma unroll
    for (int jj = 0; jj < 8; jj++){ cur0[jj] = BT[jj*NTT + r0]; cur1[jj] = BT[jj*NTT + r1]; }
    for (int ib = 0; ib < 16; ib++){
        float2 n0[8], n1[8];
        if (ib < 15){
            int nb = (ib + 1)*8;
            #pragma unroll
            for (int jj = 0; jj < 8; jj++){ n0[jj] = BT[(nb + jj)*NTT + r0]; n1[jj] = BT[(nb + jj)*NTT + r1]; }
        }
        #pragma unroll
        for (int jj = 0; jj < 8; jj++){
            int i = ib*8 + jj;
            float xr, xi;
            if (i < 64){ xr = __shfl(b0.x, i);      xi = __shfl(b0.y, i); }
            else       { xr = __shfl(b1.x, i - 64); xi = __shfl(b1.y, i - 64); }
            float2 rc = rc_s[i];
            float tr = rc.x*xr - rc.y*xi, ti = rc.x*xi + rc.y*xr;
            float2 l0 = cur0[jj], l1 = cur1[jj];
            if (r0 > i){ b0.x -= l0.x*tr - l0.y*ti; b0.y -= l0.x*ti + l0.y*tr; }
            if (r1 > i){ b1.x -= l1.x*tr - l1.y*ti; b1.y -= l1.x*ti + l1.y*tr; }
        }
        if (ib < 15){
            #pragma unroll
            for (int jj = 0; jj < 8; jj++){ cur0[jj] = n0[jj]; cur1[jj] = n1[jj]; }
        }
    }
    // -------- backward: U --------
    #pragma unroll
    for (int jj = 0; jj < 8; jj++){ cur0[jj] = BT[(120 + jj)*NTT + r0]; cur1[jj] = BT[(120 + jj)*NTT + r1]; }
    for (int ib = 15; ib >= 0; ib--){
        float2 n0[8], n1[8];
        if (ib > 0){
            int nb = (ib - 1)*8;
            #pragma unroll
            for (int jj = 0; jj < 8; jj++){ n0[jj] = BT[(nb + jj)*NTT + r0]; n1[jj] = BT[(nb + jj)*NTT + r1]; }
        }
        #pragma unroll
        for (int jj = 7; jj >= 0; jj--){
            int i = ib*8 + jj;
            float yr, yi;
            if (i < 64){ yr = __shfl(b0.x, i);      yi = __shfl(b0.y, i); }
            else       { yr = __shfl(b1.x, i - 64); yi = __shfl(b1.y, i - 64); }
            float2 rc = rc_s[i];
            float xr = rc.x*yr - rc.y*yi, xi = rc.x*yi + rc.y*yr;
            if (r0 == i){ b0.x = xr; b0.y = xi; }
            if (r1 == i){ b1.x = xr; b1.y = xi; }
            float2 u0 = cur0[jj], u1v = cur1[jj];
            if (r0 < i){ b0.x -= u0.x*xr - u0.y*xi; b0.y -= u0.x*xi + u0.y*xr; }
            if (r1 < i){ b1.x -= u1v.x*xr - u1v.y*xi; b1.y -= u1v.x*xi + u1v.y*xr; }
        }
        if (ib > 0){
            #pragma unroll
            for (int jj = 0; jj < 8; jj++){ cur0[jj] = n0[jj]; cur1[jj] = n1[jj]; }
        }
    }
    xv[r0] = b0;
    xv[r1] = b1;
}

// ---------------- fused solve + Y matvec + combine + next-layer Z (mid layers) ----------------
// Blocks 0..127: solve column k, Y matvec, combine using Zcur.
// Blocks 128..255: compute Z for layer l+1 into Znext (skipped when p4n == null).
__global__ void __launch_bounds__(512) k_solvemv(const float2* __restrict__ BT,
                                                 const float2* __restrict__ rcg,
                                                 const int* __restrict__ permg,
                                                 const float* __restrict__ Hre, const float* __restrict__ Him,
                                                 const float* __restrict__ p2re, const float* __restrict__ p2im,
                                                 const float2* __restrict__ Zcur,
                                                 const float* __restrict__ sre, const float* __restrict__ sim,
                                                 const float* __restrict__ p1re, const float* __restrict__ p1im,
                                                 float2* __restrict__ VN, float* __restrict__ pw2,
                                                 const float* __restrict__ p4nre, const float* __restrict__ p4nim,
                                                 float2* __restrict__ Znext)
{
    if (blockIdx.x >= 128){
        if (p4nre) z_body(blockIdx.x - 128, threadIdx.x, p4nre, p4nim, Hre, Him, Znext);
        return;
    }
    int k = blockIdx.x;
    int t = threadIdx.x;
    __shared__ float2 xv[NTT];
    __shared__ float2 rc_s[KK];
    __shared__ float red[8];

    // issue p2 loads early (independent of the solve)
    int r = t >> 2, q = t & 3;
    const float* mre = p2re + (size_t)k*16384 + (size_t)r*128 + q*32;
    const float* mim = p2im + (size_t)k*16384 + (size_t)r*128 + q*32;
    float4 pa[8], pb[8];
    #pragma unroll
    for (int ii = 0; ii < 8; ++ii){
        pa[ii] = *(const float4*)(mre + 4*ii);
        pb[ii] = *(const float4*)(mim + 4*ii);
    }
    if (t < 64){
        rc_s[t] = rcg[t];
        rc_s[t + 64] = rcg[t + 64];
        solve_col(BT, rc_s, permg, Hre, Him, k, t, xv);
    }
    __syncthreads();

    float ar = 0.f, ai = 0.f;
    #pragma unroll
    for (int ii = 0; ii < 8; ++ii){
        float4 a = pa[ii], b = pb[ii];
        float2 x0 = xv[q*32 + 4*ii], x1 = xv[q*32 + 4*ii + 1];
        float2 x2 = xv[q*32 + 4*ii + 2], x3 = xv[q*32 + 4*ii + 3];
        ar += a.x*x0.x - b.x*x0.y;  ai += a.x*x0.y + b.x*x0.x;
        ar += a.y*x1.x - b.y*x1.y;  ai += a.y*x1.y + b.y*x1.x;
        ar += a.z*x2.x - b.z*x2.y;  ai += a.z*x2.y + b.z*x2.x;
        ar += a.w*x3.x - b.w*x3.y;  ai += a.w*x3.y + b.w*x3.x;
    }
    ar += __shfl_xor(ar, 1); ai += __shfl_xor(ai, 1);
    ar += __shfl_xor(ar, 2); ai += __shfl_xor(ai, 2);
    float pwl = 0.f;
    if (q == 0){
        float2 z = Zcur[k*NTT + r];
        c32 s = make_float2(sre[k], sim[k]);
        float2 y = make_float2(ar + 0.01f*z.x, ai + 0.01f*z.y);
        c32 v = cmul(s, y);
        v.x += p1re[k*NTT + r]; v.y += p1im[k*NTT + r];
        VN[k*NTT + r] = v;
        pwl = v.x*v.x + v.y*v.y;
    }
    for (int d = 32; d; d >>= 1) pwl += __shfl_down(pwl, d);
    int lane = t & 63, w = t >> 6;
    if (!lane) red[w] = pwl;
    __syncthreads();
    if (!t){
        float tt = 0.f;
        #pragma unroll
        for (int w2 = 0; w2 < 8; ++w2) tt += red[w2];
        atomicAdd(pw2, tt);
    }
}

// ---------------- fused solve + final output (final layer) ----------------
__global__ void __launch_bounds__(64) k_solvefin(const float2* __restrict__ BT,
                                                 const float2* __restrict__ rcg,
                                                 const int* __restrict__ permg,
                                                 const float* __restrict__ Hre, const float* __restrict__ Him,
                                                 const float* __restrict__ sre, const float* __restrict__ sim,
                                                 float2* __restrict__ VN, float* __restrict__ pw2)
{
    int c = blockIdx.x;
    int lane = threadIdx.x;
    __shared__ float2 xv[NTT];
    __shared__ float2 rc_s[KK];
    rc_s[lane] = rcg[lane];
    rc_s[lane + 64] = rcg[lane + 64];
    solve_col(BT, rc_s, permg, Hre, Him, c, lane, xv);

    c32 s = make_float2(sre[c], sim[c]);
    float2 v0 = cmul(s, xv[lane]);
    float2 v1 = cmul(s, xv[lane + 64]);
    VN[c*NTT + lane] = v0;
    VN[c*NTT + lane + 64] = v1;
    float pwl = v0.x*v0.x + v0.y*v0.y + v1.x*v1.x + v1.y*v1.y;
    for (int d = 32; d; d >>= 1) pwl += __shfl_down(pwl, d);
    if (!lane) atomicAdd(pw2, pwl);
}

// ---------------- output write (normalized, split planes) ----------------
__global__ void k_write(const float2* __restrict__ VN, const float* __restrict__ pw2,
                        float* __restrict__ out)
{
    float gsc = sqrtf(PMAXF / *pw2);
    for (int e = blockIdx.x*blockDim.x + threadIdx.x; e < KK*NTT; e += gridDim.x*blockDim.x){
        float2 v = VN[e];
        out[e] = gsc*v.x;
        out[KK*NTT + e] = gsc*v.y;
    }
}

extern "C" void kernel_launch(void* const* d_in, const int* in_sizes, int n_in,
                              void* d_out, int out_size, void* d_ws, size_t ws_size,
                              hipStream_t stream)
{
    const float* V0  = (const float*)d_in[0];
    const float* H   = (const float*)d_in[1];
    const float* mu1 = (const float*)d_in[2];
    const float* mu3 = (const float*)d_in[3];
    const float* mu4 = (const float*)d_in[4];
    const float* mw1 = (const float*)d_in[5];
    const float* mw3 = (const float*)d_in[6];
    const float* mv1 = (const float*)d_in[7];
    const float* mv2 = (const float*)d_in[8];
    const float* mv4 = (const float*)d_in[9];
    const float* fu1 = (const float*)d_in[10];
    const float* fu3 = (const float*)d_in[11];
    const float* fu4 = (const float*)d_in[12];
    const float* fw1 = (const float*)d_in[13];
    const float* fw3 = (const float*)d_in[14];

    float* ws = (float*)d_ws;
    float*  acc  = ws;                       // [9][4]: sumw_re, sumw_im, pw2, pad ; trvv at ws[40]
    float*  wre  = ws + 64;
    float*  wim  = ws + 192;
    float*  sre  = ws + 320;
    float*  sim  = ws + 448;
    float2* B    = (float2*)(ws + 1024);     // 16384 complex
    float2* rc   = (float2*)(ws + 33792);    // 128
    int*    perm = (int*)  (ws + 34048);     // 128
    float2* Zb1  = (float2*)(ws + 34176);    // 16384 complex
    float2* Zb0  = (float2*)(ws + 99712);    // 16384 complex
    float2* VN   = (float2*)(ws + 132480);   // 16384
    float2* BT   = (float2*)(ws + 165248);   // 16384

    const int LU_LDS = KK*LDA2*sizeof(float2);   // 133,120 B dynamic
    (void)hipFuncSetAttribute((const void*)k_lu17,
                              hipFuncAttributeMaxDynamicSharedMemorySize, LU_LDS);

    hipMemsetAsync(ws, 0, 64*sizeof(float), stream);
    k_trvv<<<64, 256, 0, stream>>>(V0, ws + 40);

    const float* Hre = H;
    const float* Him = H + 16384;

    // Z for layer 0
    k_z<<<128, 512, 0, stream>>>(mv4, mv4 + 2097152, Hre, Him, Zb0);

    for (int l = 0; l < 9; l++){
        bool fin = (l == 8);
        const float* u1 = fin ? fu1 : mu1 + (size_t)l*256;
        const float* u3 = fin ? fu3 : mu3 + (size_t)l*256;
        const float* u4 = fin ? fu4 : mu4 + (size_t)l*256;
        const float* w1 = fin ? fw1 : mw1 + (size_t)l*256;
        const float* w3 = fin ? fw3 : mw3 + (size_t)l*256;

        k_stage1<<<128, 128, 0, stream>>>(Hre, Him, V0, V0 + 16384, VN, (l > 0) ? 1 : 0,
                                          (l > 0) ? (acc + (l - 1)*4 + 2) : nullptr,
                                          ws + 40,
                                          u1, u3, u4, w1, w3,
                                          wre, wim, sre, sim, acc + l*4);
        k_bbuild<<<128, 128, 0, stream>>>(Hre, Him, wre, wim, acc + l*4, B);
        k_lu17<<<1, 512, LU_LDS, stream>>>(B, BT, rc, perm);

        if (!fin){
            const float* p2 = mv2 + (size_t)l*4194304;
            const float* p1 = mv1 + (size_t)l*32768;
            float2* Zcur  = (l & 1) ? Zb1 : Zb0;
            float2* Znext = (l & 1) ? Zb0 : Zb1;
            const float* p4n = (l + 1 < 8) ? (mv4 + (size_t)(l + 1)*4194304) : nullptr;
            k_solvemv<<<256, 512, 0, stream>>>(BT, rc, perm, Hre, Him,
                                               p2, p2 + 2097152, Zcur,
                                               sre, sim, p1, p1 + 16384,
                                               VN, acc + l*4 + 2,
                                               p4n, p4n ? (p4n + 2097152) : nullptr, Znext);
        } else {
            k_solvefin<<<128, 64, 0, stream>>>(BT, rc, perm, Hre, Him,
                                               sre, sim, VN, acc + l*4 + 2);
            k_write<<<64, 256, 0, stream>>>(VN, acc + l*4 + 2, (float*)d_out);
        }
    }
}